// Round 11
// baseline (112.462 us; speedup 1.0000x reference)
//
#include <hip/hip_runtime.h>
#include <hip/hip_fp16.h>
#include <math.h>

#define HD 128
#define WD 128
#define WP 130              // padded width/height (1-halo)
#define CIN 64
#define COUT 64
#define NB 4
#define K2 9
#define HW (HD*WD)          // 16384
#define CK 576              // CIN*K2, K of both GEMMs (k-major permuted: r' = k*64+c)
#define TP 32               // pixels per block (fused kernel)
#define TPF 16              // pixels per block (fallback kernel)
#define NKK 18              // K-steps of 32
#define NTASK (K2*TP)       // 288

#define WAM   (4 * NKK * 64 * 8)             // 36864 shorts main A-frag buffer (hi only)
#define WAO   (2 * NKK * 64 * 8)             // 18432 shorts offset A-frag buffer (hi only)
#define XTP   ((size_t)NB * WP * WP * CIN)   // 4326400 shorts (padded NHWC bf16 x)
#define OFFSZ ((size_t)NB * K2 * HW)         // fallback
#define WTSZ  ((size_t)CK * COUT)            // fallback

// pre_kernel block partition
#define PRE_T 1024                            // transpose blocks
#define PRE_H 65                              // halo-zero blocks
#define PRE_P ((WAM + WAO) / 256)             // 216 prep blocks
#define HALO_PER_N 33024                      // halo shorts per image
#define HALO_W8 16512                         // total 8-short zero units

typedef __attribute__((ext_vector_type(8))) short short8;
typedef __attribute__((ext_vector_type(4))) float f32x4;

__device__ inline unsigned short f2bf(float v) {
    unsigned int u = __float_as_uint(v);
    unsigned int r = u + 0x7fffu + ((u >> 16) & 1u);
    return (unsigned short)(r >> 16);
}
__device__ inline float bf2f(unsigned short b) {
    return __uint_as_float(((unsigned int)b) << 16);
}
__device__ inline unsigned int pack_bf16(float a, float b) {
#if __has_builtin(__builtin_amdgcn_cvt_pk_bf16_f32)
    auto r = __builtin_amdgcn_cvt_pk_bf16_f32(a, b);
    unsigned int u; __builtin_memcpy(&u, &r, 4); return u;
#else
    return ((unsigned int)f2bf(b) << 16) | (unsigned int)f2bf(a);
#endif
}
// unpack dword of 2 bf16 -> float2
__device__ inline float2 up2(unsigned int u) {
    float2 r;
    r.x = __uint_as_float(u << 16);
    r.y = __uint_as_float(u & 0xffff0000u);
    return r;
}

// ---------------- merged pre-kernel: transpose | halo zero | weight prep ----------------
__global__ __launch_bounds__(256) void pre_kernel(
    const float* __restrict__ x,
    const float* __restrict__ weight,
    const float* __restrict__ w_off,
    const float* __restrict__ w_mask,
    unsigned short* __restrict__ xp,
    short* __restrict__ mhi, short* __restrict__ ohi)
{
    __shared__ float tile[64][66];   // [w][c], pad 66
    int bid = blockIdx.x;
    int t = threadIdx.x;

    if (bid < PRE_T) {
        int half = bid & 1;
        int h = (bid >> 1) & 127;
        int n = bid >> 8;
        int w0 = half * 64;
        int g = t >> 6, wl = t & 63;
        const float* xb = x + ((size_t)n * CIN) * HW + h * WD + w0;
        #pragma unroll
        for (int i = 0; i < 16; i++) {
            int cc = i * 4 + g;
            tile[wl][cc] = xb[(size_t)cc * HW + wl];
        }
        __syncthreads();
        size_t rowbase = (((size_t)n * WP + (h + 1)) * WP + (w0 + 1)) * CIN;
        #pragma unroll
        for (int i = 0; i < 8; i++) {
            int u = i * 256 + t;
            int ww = u >> 5;
            int cp = (u & 31) * 2;
            float2 v = *(const float2*)&tile[ww][cp];
            *(unsigned int*)&xp[rowbase + (size_t)ww * CIN + cp] = pack_bf16(v.x, v.y);
        }
    } else if (bid < PRE_T + PRE_H) {
        int widx = (bid - PRE_T) * 256 + t;
        if (widx < HALO_W8) {
            int s = widx * 8;
            int n = s / HALO_PER_N;
            int v = s - n * HALO_PER_N;
            size_t nb = (size_t)n * WP * WP * CIN;
            size_t base;
            if (v < 8320) {
                base = nb + v;
            } else if (v < 16640) {
                base = nb + (size_t)129 * WP * CIN + (v - 8320);
            } else if (v < 24832) {
                int v2 = v - 16640; int h = 1 + (v2 >> 6); int c = v2 & 63;
                base = nb + (size_t)h * WP * CIN + c;
            } else {
                int v3 = v - 24832; int h = 1 + (v3 >> 6); int c = v3 & 63;
                base = nb + ((size_t)h * WP + 129) * CIN + c;
            }
            short8 z = {0, 0, 0, 0, 0, 0, 0, 0};
            *(short8*)&xp[base] = z;
        }
    } else {
        int gid = (bid - PRE_T - PRE_H) * 256 + t;
        if (gid < WAM) {
            int idx = gid;
            int jj = idx & 7;
            int lane = (idx >> 3) & 63;
            int kk = (idx >> 9) % NKK;
            int mt = (idx >> 9) / NKK;
            int o = mt * 16 + (lane & 15);
            int rp = kk * 32 + (lane >> 4) * 8 + jj;
            int k = rp >> 6, c = rp & 63;
            mhi[idx] = (short)f2bf(weight[((size_t)o * CIN + c) * 9 + k]);
        } else {
            int idx = gid - WAM;
            int jj = idx & 7;
            int lane = (idx >> 3) & 63;
            int kk = (idx >> 9) % NKK;
            int mt = (idx >> 9) / NKK;
            int j = mt * 16 + (lane & 15);
            int rp = kk * 32 + (lane >> 4) * 8 + jj;
            int k = rp >> 6, c = rp & 63;
            float w = 0.f;
            if (j < 18)      w = w_off[((size_t)j * CIN + c) * 9 + k];
            else if (j < 27) w = w_mask[((size_t)(j - 18) * CIN + c) * 9 + k];
            ohi[idx] = (short)f2bf(w);
        }
    }
}

// ---------------- fused kernel, TP=32, LDS diet (40320 B -> 4 blocks/CU) ----------------
// grid (WD/TP=4, HD, NB), block 256.
__global__ __launch_bounds__(256, 4) void fused_kernel(
    const unsigned short* __restrict__ xp,
    const short* __restrict__ waM_hi,
    const short* __restrict__ waO_hi,
    const float* __restrict__ b_off, const float* __restrict__ b_mask,
    const float* __restrict__ bias,
    float* __restrict__ out)
{
    // B operand: 72 chunks x (32 p-slots x 8 jj) bf16, slot = (p + c2) & 31
    __shared__ __align__(16) short val_hi[72 * 256];     // 36864 B
    // union region (3456 B): stages 2-3a = conv_s float[27*32];
    // stages 3b-4 = packed params: [0,576) weight half2 pairs, [576,864) idx
    __shared__ __align__(16) unsigned int uparam[864];

    int t = threadIdx.x;
    int wv = t >> 6;
    int lane = t & 63;
    int wo0 = blockIdx.x * TP;
    int ho  = blockIdx.y;
    int n   = blockIdx.z;
    const unsigned short* xpn = xp + (size_t)n * WP * WP * CIN;
    int p16 = lane & 15, quad = lane >> 4;
    float* conv_s = (float*)uparam;

    // ---- stage 1: patch -> B-frag layout; 2304 16B copies (9 exact iters) ----
    #pragma unroll
    for (int i = 0; i < 9; i++) {
        int u = t + 256 * i;
        int tap = u >> 8;
        int p = (u >> 3) & 31;
        int g = u & 7;
        int ti = tap / 3, tj = tap - ti * 3;
        const short8 v = *(const short8*)&xpn[((size_t)(ho + ti) * WP + (wo0 + p + tj)) * CIN + g * 8];
        int c2 = tap * 8 + g;
        *(short8*)&val_hi[c2 * 256 + ((p + c2) & 31) * 8] = v;
    }
    __syncthreads();

    // ---- stage 2: offset/mask conv GEMM; wave = (jt, pt); single-A chain ----
    {
        int jt = wv >> 1, pt = wv & 1;
        f32x4 acc = {0.f, 0.f, 0.f, 0.f};
        #pragma unroll
        for (int kk = 0; kk < NKK; kk++) {
            int abase = ((jt * NKK + kk) * 64 + lane) * 8;
            short8 ah = *(const short8*)&waO_hi[abase];
            int c2 = kk * 4 + quad;
            short8 b = *(const short8*)&val_hi[c2 * 256 + ((pt * 16 + p16 + c2) & 31) * 8];
            acc = __builtin_amdgcn_mfma_f32_16x16x32_bf16(ah, b, acc, 0, 0, 0);
        }
        #pragma unroll
        for (int i = 0; i < 4; i++) {
            int j = jt * 16 + quad * 4 + i;
            if (j < 27) {
                float bv = (j < 18) ? b_off[j] : b_mask[j - 18];
                conv_s[j * 32 + pt * 16 + p16] = acc[i] + bv;
            }
        }
    }
    __syncthreads();

    // ---- stage 3a: sigmoid-modulated offsets -> packed bilinear params in regs ----
    unsigned int r_w01[2], r_w23[2], r_idx[2];
    #pragma unroll
    for (int pass = 0; pass < 2; pass++) {
        int u = t + pass * 256;
        if (u < NTASK) {
            int k = u >> 5, p = u & 31;
            float oy_raw = conv_s[(2 * k) * 32 + p];
            float ox_raw = conv_s[(2 * k + 1) * 32 + p];
            float my = 1.f / (1.f + expf(-conv_s[(18 + (2 * k) % 9) * 32 + p]));
            float mx = 1.f / (1.f + expf(-conv_s[(18 + (2 * k + 1) % 9) * 32 + p]));
            float oy = oy_raw * my;
            float ox = ox_raw * mx;
            int ki = k / 3, kj = k - ki * 3;
            int wo = wo0 + p;
            float py = (float)(ho - 1 + ki) + oy;
            float px = (float)(wo - 1 + kj) + ox;
            float y0f = floorf(py), x0f = floorf(px);
            float wy = py - y0f, wx = px - x0f;
            int y0 = (int)y0f, x0 = (int)x0f;
            float wy0 = 1.f - wy, wx0 = 1.f - wx;
            int y0c = min(max(y0, 0), HD - 1);
            int y1c = min(max(y0 + 1, 0), HD - 1);
            int x0c = min(max(x0, 0), WD - 1);
            int x1c = min(max(x0 + 1, 0), WD - 1);
            bool vy0 = (y0 >= 0) && (y0 < HD);
            bool vy1 = (y0 + 1 >= 0) && (y0 + 1 < HD);
            bool vx0 = (x0 >= 0) && (x0 < WD);
            bool vx1 = (x0 + 1 >= 0) && (x0 + 1 < WD);
            float wa = (vy0 && vx0) ? wy0 * wx0 : 0.f;
            float wb = (vy0 && vx1) ? wy0 * wx  : 0.f;
            float wc = (vy1 && vx0) ? wy  * wx0 : 0.f;
            float wd = (vy1 && vx1) ? wy  * wx  : 0.f;
            __half2 h01 = __floats2half2_rn(wa, wb);
            __half2 h23 = __floats2half2_rn(wc, wd);
            __builtin_memcpy(&r_w01[pass], &h01, 4);
            __builtin_memcpy(&r_w23[pass], &h23, 4);
            unsigned int base = (unsigned int)(((y0c + 1) * WP + (x0c + 1)) * CIN);
            if (x1c > x0c) base |= (1u << 30);
            if (y1c > y0c) base |= (1u << 31);
            r_idx[pass] = base;
        }
    }
    __syncthreads();   // all conv_s reads done; union becomes params

    // ---- stage 3b: write packed params ----
    #pragma unroll
    for (int pass = 0; pass < 2; pass++) {
        int u = t + pass * 256;
        if (u < NTASK) {
            uparam[2 * u] = r_w01[pass];
            uparam[2 * u + 1] = r_w23[pass];
            uparam[2 * NTASK + u] = r_idx[pass];
        }
    }
    __syncthreads();

    // ---- stage 4: bilinear gather, 8 channels/lane, dwordx4 loads + ds_write_b128 ----
    #pragma unroll
    for (int i = 0; i < 9; i++) {
        int u = t + 256 * i;
        int task = u >> 3;
        int g = u & 7;
        int c0 = g * 8;
        int k = task >> 5, p = task & 31;
        unsigned int w01 = uparam[2 * task];
        unsigned int w23 = uparam[2 * task + 1];
        unsigned int pk = uparam[2 * NTASK + task];
        __half2 h01, h23;
        __builtin_memcpy(&h01, &w01, 4);
        __builtin_memcpy(&h23, &w23, 4);
        float wa = __low2float(h01), wb = __high2float(h01);
        float wc = __low2float(h23), wd = __high2float(h23);
        int base = (int)(pk & 0x3fffffffu) + c0;
        int dx = (pk & (1u << 30)) ? CIN : 0;
        int dyo = (pk & (1u << 31)) ? WP * CIN : 0;
        uint4 qa = *(const uint4*)&xpn[base];
        uint4 qb = *(const uint4*)&xpn[base + dx];
        uint4 qc = *(const uint4*)&xpn[base + dyo];
        uint4 qd = *(const uint4*)&xpn[base + dyo + dx];
        unsigned int qa_[4] = {qa.x, qa.y, qa.z, qa.w};
        unsigned int qb_[4] = {qb.x, qb.y, qb.z, qb.w};
        unsigned int qc_[4] = {qc.x, qc.y, qc.z, qc.w};
        unsigned int qd_[4] = {qd.x, qd.y, qd.z, qd.w};
        unsigned int r_[4];
        #pragma unroll
        for (int d = 0; d < 4; d++) {
            float2 fa = up2(qa_[d]), fb = up2(qb_[d]), fc = up2(qc_[d]), fd = up2(qd_[d]);
            float2 gg;
            gg.x = wa * fa.x + wb * fb.x + wc * fc.x + wd * fd.x;
            gg.y = wa * fa.y + wb * fb.y + wc * fc.y + wd * fd.y;
            r_[d] = pack_bf16(gg.x, gg.y);
        }
        uint4 r = {r_[0], r_[1], r_[2], r_[3]};
        int c2 = k * 8 + g;
        *(uint4*)&val_hi[c2 * 256 + ((p + c2) & 31) * 8] = r;
    }
    __syncthreads();

    // ---- stage 5: main GEMM C[64 o][32 p]; single-A reused across both p-tiles ----
    f32x4 a0 = {0.f, 0.f, 0.f, 0.f};
    f32x4 a1 = {0.f, 0.f, 0.f, 0.f};
    #pragma unroll
    for (int kk = 0; kk < NKK; kk++) {
        int abase = ((wv * NKK + kk) * 64 + lane) * 8;
        short8 ah = *(const short8*)&waM_hi[abase];
        int c2 = kk * 4 + quad;
        short8 b0 = *(const short8*)&val_hi[c2 * 256 + ((p16 + c2) & 31) * 8];
        short8 b1 = *(const short8*)&val_hi[c2 * 256 + ((16 + p16 + c2) & 31) * 8];
        a0 = __builtin_amdgcn_mfma_f32_16x16x32_bf16(ah, b0, a0, 0, 0, 0);
        a1 = __builtin_amdgcn_mfma_f32_16x16x32_bf16(ah, b1, a1, 0, 0, 0);
    }

    // ---- epilogue: direct stores ----
    size_t obase = ((size_t)n * COUT) * HW + (size_t)ho * WD + wo0;
    #pragma unroll
    for (int i = 0; i < 4; i++) {
        int o = wv * 16 + quad * 4 + i;
        float bv = bias[o];
        out[obase + (size_t)o * HW + p16] = a0[i] + bv;
        out[obase + (size_t)o * HW + 16 + p16] = a1[i] + bv;
    }
}

// ================= fallback path (R1-proven, fp32 NCHW, TPF=16) =================
__global__ void transpose_w_kernel(const float* __restrict__ w, float* __restrict__ wt) {
    int i = blockIdx.x * 256 + threadIdx.x;
    int o = i / CK;
    int ck = i - o * CK;
    wt[ck * COUT + o] = w[i];
}

__global__ __launch_bounds__(256) void offmask_kernel(
    const float* __restrict__ x,
    const float* __restrict__ w_off, const float* __restrict__ b_off,
    const float* __restrict__ w_mask, const float* __restrict__ b_mask,
    float* __restrict__ offy, float* __restrict__ offx)
{
    __shared__ float ws[CK][27];
    int t = threadIdx.x;
    for (int i = t; i < CK * 27; i += 256) {
        int j = i % 27;
        int citap = i / 27;
        int ci = citap / 9;
        int tap = citap - ci * 9;
        float v;
        if (j < 18) v = w_off[(j * CIN + ci) * 9 + tap];
        else        v = w_mask[((j - 18) * CIN + ci) * 9 + tap];
        ws[citap][j] = v;
    }
    __syncthreads();

    int pix = blockIdx.x * 256 + t;
    int n  = pix >> 14;
    int ho = (pix >> 7) & 127;
    int wo = pix & 127;

    float acc[27];
    #pragma unroll
    for (int j = 0; j < 18; j++) acc[j] = b_off[j];
    #pragma unroll
    for (int j = 0; j < 9; j++)  acc[18 + j] = b_mask[j];

    int offs[9];
    bool oks[9];
    #pragma unroll
    for (int dy = 0; dy < 3; dy++) {
        int y = ho - 1 + dy;
        #pragma unroll
        for (int dx = 0; dx < 3; dx++) {
            int xx = wo - 1 + dx;
            bool ok = (y >= 0) && (y < HD) && (xx >= 0) && (xx < WD);
            oks[dy * 3 + dx] = ok;
            offs[dy * 3 + dx] = (ok ? y : 0) * WD + (ok ? xx : 0);
        }
    }
    const float* xn = x + (size_t)n * CIN * HW;
    for (int ci = 0; ci < CIN; ci++) {
        const float* xc = xn + (size_t)ci * HW;
        float v[9];
        #pragma unroll
        for (int tap = 0; tap < 9; tap++)
            v[tap] = oks[tap] ? xc[offs[tap]] : 0.f;
        #pragma unroll
        for (int tap = 0; tap < 9; tap++) {
            const float* wrow = ws[ci * 9 + tap];
            float vv = v[tap];
            #pragma unroll
            for (int j = 0; j < 27; j++) acc[j] += wrow[j] * vv;
        }
    }
    float m[9];
    #pragma unroll
    for (int j = 0; j < 9; j++) m[j] = 1.f / (1.f + expf(-acc[18 + j]));
    #pragma unroll
    for (int k = 0; k < 9; k++) {
        int cy = 2 * k, cx = 2 * k + 1;
        float my = m[cy < 9 ? cy : cy - 9];
        float mx = m[cx < 9 ? cx : cx - 9];
        size_t o = (((size_t)n * K2 + k) * HD + ho) * WD + wo;
        offy[o] = acc[cy] * my;
        offx[o] = acc[cx] * mx;
    }
}

__global__ __launch_bounds__(256) void deform_kernel(
    const float* __restrict__ x,
    const float* __restrict__ offy, const float* __restrict__ offx,
    const float* __restrict__ wt,
    const float* __restrict__ bias,
    float* __restrict__ out)
{
    __shared__ __align__(16) float val_s[CK * TPF];
    __shared__ float4 p_w4[K2 * TPF];
    __shared__ int4   p_idx4[K2 * TPF];

    int t = threadIdx.x;
    int wo0 = blockIdx.x * TPF;
    int ho  = blockIdx.y;
    int n   = blockIdx.z;

    if (t < K2 * TPF) {
        int k = t >> 4, p = t & 15;
        int wo = wo0 + p;
        size_t oi = (((size_t)n * K2 + k) * HD + ho) * WD + wo;
        float oy = offy[oi], ox = offx[oi];
        int ki = k / 3, kj = k - ki * 3;
        float py = (float)(ho - 1 + ki) + oy;
        float px = (float)(wo - 1 + kj) + ox;
        float y0f = floorf(py), x0f = floorf(px);
        float wy = py - y0f, wx = px - x0f;
        int y0 = (int)y0f, x0 = (int)x0f;
        float wy0 = 1.f - wy, wx0 = 1.f - wx;
        int y0c = min(max(y0, 0), HD - 1);
        int y1c = min(max(y0 + 1, 0), HD - 1);
        int x0c = min(max(x0, 0), WD - 1);
        int x1c = min(max(x0 + 1, 0), WD - 1);
        bool vy0 = (y0 >= 0) && (y0 < HD);
        bool vy1 = (y0 + 1 >= 0) && (y0 + 1 < HD);
        bool vx0 = (x0 >= 0) && (x0 < WD);
        bool vx1 = (x0 + 1 >= 0) && (x0 + 1 < WD);
        float4 w4;
        w4.x = (vy0 && vx0) ? wy0 * wx0 : 0.f;
        w4.y = (vy0 && vx1) ? wy0 * wx  : 0.f;
        w4.z = (vy1 && vx0) ? wy  * wx0 : 0.f;
        w4.w = (vy1 && vx1) ? wy  * wx  : 0.f;
        int4 i4;
        i4.x = y0c * WD + x0c;
        i4.y = y0c * WD + x1c;
        i4.z = y1c * WD + x0c;
        i4.w = y1c * WD + x1c;
        p_w4[t] = w4;
        p_idx4[t] = i4;
    }
    __syncthreads();

    const float* xn = x + (size_t)n * CIN * HW;
    for (int e = t; e < CK * TPF; e += 256) {
        int row = e >> 4, p = e & 15;
        int cc = row / 9, k = row - cc * 9;
        int task = (k << 4) | p;
        float4 w4 = p_w4[task];
        int4  i4 = p_idx4[task];
        const float* xc = xn + (size_t)cc * HW;
        val_s[e] = w4.x * xc[i4.x] + w4.y * xc[i4.y]
                 + w4.z * xc[i4.z] + w4.w * xc[i4.w];
    }
    __syncthreads();

    int o = t & 63, q = t >> 6;
    float4 acc = {0.f, 0.f, 0.f, 0.f};
    const float4* v4 = (const float4*)val_s;
    const float* wp = wt + o;
    #pragma unroll 4
    for (int r = 0; r < CK; r++) {
        float w = wp[r * COUT];
        float4 vv = v4[r * 4 + q];
        acc.x += w * vv.x; acc.y += w * vv.y;
        acc.z += w * vv.z; acc.w += w * vv.w;
    }
    float b = bias[o];
    acc.x += b; acc.y += b; acc.z += b; acc.w += b;
    __syncthreads();
    float4* o4 = (float4*)val_s;
    o4[o * 4 + q] = acc;
    __syncthreads();
    size_t obase = ((size_t)n * COUT) * HW + (size_t)ho * WD + wo0;
    #pragma unroll
    for (int i = 0; i < 4; i++) {
        int l = t + 256 * i;
        int oo = l >> 4, p = l & 15;
        out[obase + (size_t)oo * HW + p] = val_s[l];
    }
}

extern "C" void kernel_launch(void* const* d_in, const int* in_sizes, int n_in,
                              void* d_out, int out_size, void* d_ws, size_t ws_size,
                              hipStream_t stream) {
    const float* x      = (const float*)d_in[0];
    const float* w_off  = (const float*)d_in[1];
    const float* b_off  = (const float*)d_in[2];
    const float* w_mask = (const float*)d_in[3];
    const float* b_mask = (const float*)d_in[4];
    const float* weight = (const float*)d_in[5];
    const float* bias   = (const float*)d_in[6];
    float* out = (float*)d_out;

    // ws layout (shorts): waM_hi | waO_hi | xp
    short* base = (short*)d_ws;
    short* waM_hi = base;
    short* waO_hi = waM_hi + WAM;
    unsigned short* xp = (unsigned short*)(waO_hi + WAO);
    size_t need = ((size_t)WAM + WAO + XTP) * sizeof(short);

    if (ws_size >= need) {
        pre_kernel<<<PRE_T + PRE_H + PRE_P, 256, 0, stream>>>(
            x, weight, w_off, w_mask, xp, waM_hi, waO_hi);
        fused_kernel<<<dim3(WD / TP, HD, NB), 256, 0, stream>>>(
            xp, waM_hi, waO_hi, b_off, b_mask, bias, out);
    } else {
        float* offy = (float*)d_ws;
        float* offx = offy + OFFSZ;
        float* wt   = offx + OFFSZ;
        transpose_w_kernel<<<144, 256, 0, stream>>>(weight, wt);
        offmask_kernel<<<256, 256, 0, stream>>>(x, w_off, b_off, w_mask, b_mask, offy, offx);
        deform_kernel<<<dim3(WD / TPF, HD, NB), 256, 0, stream>>>(x, offy, offx, wt, bias, out);
    }
}